// Round 4
// baseline (393.770 us; speedup 1.0000x reference)
//
#include <hip/hip_runtime.h>
#include <hip/hip_bf16.h>
#include <math.h>

#define B 8
#define HH 28
#define WDIM 28
#define PIX 784
#define PPIX 900          // 30*30 padded
#define M_TOT 6272
#define NK 9
#define C1 256
#define HID 1024
#define OUT2 256
#define K1 (C1*NK)   // 2304
#define K2 (HID*NK)  // 9216

typedef short short8_t __attribute__((ext_vector_type(8)));
typedef unsigned short us8 __attribute__((ext_vector_type(8)));
typedef float f32x4 __attribute__((ext_vector_type(4)));
typedef unsigned int u32x4 __attribute__((ext_vector_type(4)));

__device__ inline float bf2f(unsigned short u){ union{unsigned i; float f;} w; w.i=((unsigned)u)<<16; return w.f; }
__device__ inline unsigned short f2bf(float f){ union{float ff; unsigned i;} w; w.ff=f; unsigned u=w.i; return (unsigned short)((u + 0x7FFFu + ((u>>16)&1u))>>16); }

__device__ inline void gload16(const void* g, void* l) {
  __builtin_amdgcn_global_load_lds((const __attribute__((address_space(1))) void*)g,
                                   (__attribute__((address_space(3))) void*)l, 16, 0, 0);
}

// ---------------- zero fill (pad rings) ----------------
__global__ __launch_bounds__(256) void zero_kernel(u32x4* __restrict__ p, int n16)
{
  int i = blockIdx.x * 256 + threadIdx.x;
  if (i < n16) p[i] = u32x4{0u, 0u, 0u, 0u};
}

// ---------------- transpose x: [B][C][784] fp32 -> padded [B][900][C] bf16
__global__ __launch_bounds__(256) void xpose_kernel(
    const float* __restrict__ x, unsigned short* __restrict__ xclp, int C)
{
  __shared__ unsigned short tile[32][33];
  int b = blockIdx.z, c0 = blockIdx.y * 32, p0 = blockIdx.x * 32;
  int tx = threadIdx.x & 31, ty = threadIdx.x >> 5;
  for (int i = ty; i < 32; i += 8) {
    int c = c0 + i, p = p0 + tx;
    unsigned short v = 0;
    if (p < PIX) v = f2bf(x[((size_t)b * C + c) * PIX + p]);
    tile[i][tx] = v;
  }
  __syncthreads();
  for (int i = ty; i < 32; i += 8) {
    int p = p0 + i, c = c0 + tx;
    if (p < PIX) {
      int h = p / WDIM, w = p % WDIM;
      xclp[((size_t)b * PPIX + (h + 1) * 30 + (w + 1)) * C + c] = tile[tx][i];
    }
  }
}

// ---------------- w_c repack: [O][C][9] fp32 -> [O][n*C+c] bf16 -----------
__global__ __launch_bounds__(256) void wrep_kernel(
    const float* __restrict__ w, unsigned short* __restrict__ wr, int C)
{
  int o = blockIdx.x;
  int K = 9 * C;
  for (int k = threadIdx.x; k < K; k += 256) {
    int n = k / C, c = k % C;
    wr[(size_t)o * K + k] = f2bf(w[((size_t)o * C + c) * 9 + n]);
  }
}

// ---------------- pconv weight repack: -> [32][9*C] bf16 (rows 27..31 = 0)
__global__ __launch_bounds__(256) void wprep_kernel(
    const float* __restrict__ wp, const float* __restrict__ wm,
    unsigned short* __restrict__ wpr, int C)
{
  int ch = blockIdx.x;
  int K = 9 * C;
  const float* src = nullptr;
  if (ch < 18) src = wp + (size_t)ch * C * 9;
  else if (ch < 27) src = wm + (size_t)(ch - 18) * C * 9;
  for (int k = threadIdx.x; k < K; k += 256) {
    int n = k / C, c = k % C;
    unsigned short v = 0;
    if (src) v = f2bf(src[(size_t)c * 9 + n]);
    wpr[(size_t)ch * K + k] = v;
  }
}

// ---------------- pconv as skinny MFMA GEMM: [M][9C] x [32][9C]^T --------
template<int C, int KSPLIT>
__global__ __launch_bounds__(256) void pconv_mfma(
    const unsigned short* __restrict__ xclp, // [B*900][C] padded
    const unsigned short* __restrict__ wpr,  // [32][9C]
    float* __restrict__ pmpart)              // [KSPLIT][M][32]
{
  __shared__ unsigned short As[128 * 64];
  __shared__ unsigned short Ws[32 * 64];
  const int K = 9 * C;
  int t = threadIdx.x, lane = t & 63, wv = t >> 6;
  int m0 = blockIdx.x * 128;
  int kz = blockIdx.y;
  int wm = (wv & 1) * 64, wo = (wv >> 1) * 16;
  f32x4 acc[4];
  #pragma unroll
  for (int i = 0; i < 4; ++i) acc[i] = {0.f, 0.f, 0.f, 0.f};
  long pbase[4];
  #pragma unroll
  for (int i = 0; i < 4; ++i) {
    int L = i * 256 + t, row = L >> 3;
    int m = m0 + row, b = m / PIX, pix = m - b * PIX;
    int h = pix / WDIM, w = pix - h * WDIM;
    pbase[i] = ((long)b * PPIX + (h + 1) * 30 + (w + 1)) * C;
  }
  int kbeg = kz * (K / KSPLIT), kend = kbeg + K / KSPLIT;
  for (int k0 = kbeg; k0 < kend; k0 += 64) {
    int n = k0 / C, c0 = k0 - n * C;
    long doff = (long)(((n / 3) - 1) * 30 + (n % 3) - 1) * C + c0;
    __syncthreads();
    #pragma unroll
    for (int i = 0; i < 4; ++i) {
      int L = i * 256 + t, row = L >> 3, ch = L & 7;
      const char* src = (const char*)(xclp + pbase[i] + doff) + ((ch ^ (row & 7)) << 4);
      gload16(src, (char*)As + (size_t)(i * 256 + (wv << 6)) * 16);
    }
    {
      int row = t >> 3, ch = t & 7;
      const char* src = (const char*)(wpr + (size_t)row * K + k0) + ((ch ^ (row & 7)) << 4);
      gload16(src, (char*)Ws + (size_t)(wv << 6) * 16);
    }
    __syncthreads();
    #pragma unroll
    for (int ks = 0; ks < 2; ++ks) {
      short8_t af[4], bq;
      {
        int row = wo + (lane & 15), ch = ks * 4 + (lane >> 4);
        bq = *(const short8_t*)((const char*)Ws + row * 128 + ((ch ^ (row & 7)) << 4));
      }
      #pragma unroll
      for (int fm = 0; fm < 4; ++fm) {
        int row = wm + fm * 16 + (lane & 15), ch = ks * 4 + (lane >> 4);
        af[fm] = *(const short8_t*)((const char*)As + row * 128 + ((ch ^ (row & 7)) << 4));
      }
      #pragma unroll
      for (int fm = 0; fm < 4; ++fm)
        acc[fm] = __builtin_amdgcn_mfma_f32_16x16x32_bf16(af[fm], bq, acc[fm], 0, 0, 0);
    }
  }
  float* dst = pmpart + (size_t)kz * M_TOT * 32;
  #pragma unroll
  for (int fm = 0; fm < 4; ++fm)
    #pragma unroll
    for (int r = 0; r < 4; ++r) {
      int ml = m0 + wm + fm * 16 + (lane >> 4) * 4 + r;
      int o = wo + (lane & 15);
      dst[(size_t)ml * 32 + o] = acc[fm][r];
    }
}

// ------- bilinear table: ABSOLUTE padded-pixel corner indices + gains -----
template<int KSPLIT>
__global__ __launch_bounds__(256) void mktab_kernel(
    const float* __restrict__ pmpart,
    const float* __restrict__ b_p, const float* __restrict__ b_m,
    int4* __restrict__ tabOff, float4* __restrict__ tabG)
{
  int i = blockIdx.x * 256 + threadIdx.x;
  if (i >= M_TOT * NK) return;
  int m = i / NK, n = i % NK;
  int bidx = m / PIX;
  int pix = m % PIX;
  int hh = pix / WDIM, ww = pix % WDIM;
  float ox = 0.f, oy = 0.f, om = 0.f;
  #pragma unroll
  for (int kz = 0; kz < KSPLIT; ++kz) {
    const float* q = pmpart + (size_t)kz * M_TOT * 32 + (size_t)m * 32;
    ox += q[n]; oy += q[9 + n]; om += q[18 + n];
  }
  float px = ox + b_p[n]     + (float)(hh + 1) + (float)(n / 3 - 1);
  float py = oy + b_p[9 + n] + (float)(ww + 1) + (float)(n % 3 - 1);
  float msk = 1.f / (1.f + expf(-(om + b_m[n])));
  float fx = floorf(px), fy = floorf(py);
  float qlx = fminf(fmaxf(fx, 0.f), 29.f);
  float qly = fminf(fmaxf(fy, 0.f), 29.f);
  float qrx = fminf(fmaxf(fx + 1.f, 0.f), 29.f);
  float qry = fminf(fmaxf(fy + 1.f, 0.f), 29.f);
  float pxc = fminf(fmaxf(px, 0.f), 29.f);
  float pyc = fminf(fmaxf(py, 0.f), 29.f);
  float glt = (1.f + (qlx - pxc)) * (1.f + (qly - pyc));
  float grb = (1.f - (qrx - pxc)) * (1.f - (qry - pyc));
  float glb = (1.f + (qlx - pxc)) * (1.f - (qry - pyc));
  float grt = (1.f - (qrx - pxc)) * (1.f + (qly - pyc));
  int ax = (int)qlx, ay = (int)qly, bx = (int)qrx, by = (int)qry;
  int pb = bidx * PPIX;
  tabOff[i] = make_int4(pb + ax * 30 + ay, pb + bx * 30 + by,
                        pb + ax * 30 + by, pb + bx * 30 + ay);
  tabG[i]   = make_float4(glt * msk, grb * msk, glb * msk, grt * msk);
}

// ---------------- fused deformable GEMM -----------------------------------
// A-tile is SAMPLED on the fly (4 corner gathers * gains -> bf16 -> LDS).
// Wr: [O][K] bf16.  VAR=0: hclp [B*900][O] bf16 +ReLU.  VAR=1: fp32 partials.
template<int TN, int VAR, int CIN>
__global__ __launch_bounds__(256) void dgemm_fused(
    const unsigned short* __restrict__ xclp, // [B*900][CIN] padded source
    const int4* __restrict__ tabO,           // [M][9] absolute corner idx
    const float4* __restrict__ tabG,         // [M][9] gains*mask
    const unsigned short* __restrict__ Wr,
    void* __restrict__ outv,
    int O, int ksplit)
{
  const int K = 9 * CIN;
  __shared__ unsigned short As[128 * 64];
  __shared__ unsigned short Ws[TN * 64];
  constexpr int NFO = TN / 32;
  int t = threadIdx.x, lane = t & 63, wv = t >> 6;
  int m0 = blockIdx.x * 128, o0 = blockIdx.y * TN;
  int kz = blockIdx.z;
  int wm = (wv & 1) * 64, wo = (wv >> 1) * (TN / 2);
  f32x4 acc[4][NFO];
  #pragma unroll
  for (int i = 0; i < 4; ++i)
    #pragma unroll
    for (int j = 0; j < NFO; ++j)
      acc[i][j] = {0.f, 0.f, 0.f, 0.f};

  int kn = K / ksplit;
  int kbeg = kz * kn, kend = kbeg + kn;
  for (int k0 = kbeg; k0 < kend; k0 += 64) {
    int n = k0 / CIN, c0 = k0 - n * CIN;   // 64-wide k-tile lies in one tap n
    __syncthreads();
    // W stage (async direct-to-LDS, pre-swizzled source)
    #pragma unroll
    for (int i = 0; i < TN / 32; ++i) {
      int L = i * 256 + t, row = L >> 3, ch = L & 7;
      const char* src = (const char*)(Wr + (size_t)(o0 + row) * K + k0) + ((ch ^ (row & 7)) << 4);
      gload16(src, (char*)Ws + (size_t)(i * 256 + (wv << 6)) * 16);
    }
    // A stage: bilinear-sample 128 rows x 64 ch into LDS (swizzled write)
    #pragma unroll
    for (int i = 0; i < 4; ++i) {
      int row = i * 32 + (t >> 3), ch = t & 7;
      int m = m0 + row;
      int4  o = tabO[(size_t)m * NK + n];
      float4 g = tabG[(size_t)m * NK + n];
      int cc = c0 + ch * 8;
      us8 a0 = *(const us8*)(xclp + (size_t)o.x * CIN + cc);
      us8 a1 = *(const us8*)(xclp + (size_t)o.y * CIN + cc);
      us8 a2 = *(const us8*)(xclp + (size_t)o.z * CIN + cc);
      us8 a3 = *(const us8*)(xclp + (size_t)o.w * CIN + cc);
      us8 r;
      #pragma unroll
      for (int j = 0; j < 8; ++j) {
        float v = g.x * bf2f(a0[j]) + g.y * bf2f(a1[j])
                + g.z * bf2f(a2[j]) + g.w * bf2f(a3[j]);
        r[j] = f2bf(v);
      }
      *(us8*)((char*)As + row * 128 + ((ch ^ (row & 7)) << 4)) = r;
    }
    __syncthreads();
    #pragma unroll
    for (int ks = 0; ks < 2; ++ks) {
      short8_t af[4], bfq[NFO];
      #pragma unroll
      for (int fm = 0; fm < 4; ++fm) {
        int row = wm + fm * 16 + (lane & 15), ch = ks * 4 + (lane >> 4);
        af[fm] = *(const short8_t*)((const char*)As + row * 128 + ((ch ^ (row & 7)) << 4));
      }
      #pragma unroll
      for (int fo = 0; fo < NFO; ++fo) {
        int row = wo + fo * 16 + (lane & 15), ch = ks * 4 + (lane >> 4);
        bfq[fo] = *(const short8_t*)((const char*)Ws + row * 128 + ((ch ^ (row & 7)) << 4));
      }
      #pragma unroll
      for (int fm = 0; fm < 4; ++fm)
        #pragma unroll
        for (int fo = 0; fo < NFO; ++fo)
          acc[fm][fo] = (VAR == 0)
            ? __builtin_amdgcn_mfma_f32_16x16x32_bf16(af[fm], bfq[fo], acc[fm][fo], 0, 0, 0)
            : __builtin_amdgcn_mfma_f32_16x16x32_bf16(bfq[fo], af[fm], acc[fm][fo], 0, 0, 0);
    }
  }

  if (VAR == 0) {
    unsigned short* hcl = (unsigned short*)outv;
    #pragma unroll
    for (int fm = 0; fm < 4; ++fm)
      #pragma unroll
      for (int r = 0; r < 4; ++r) {
        int ml = m0 + wm + fm * 16 + (lane >> 4) * 4 + r;
        int m = ml, b = m / PIX, pix = m - b * PIX;
        int h = pix / WDIM, w = pix - h * WDIM;
        size_t base = ((size_t)b * PPIX + (h + 1) * 30 + (w + 1)) * (size_t)O;
        #pragma unroll
        for (int fo = 0; fo < NFO; ++fo) {
          int o = o0 + wo + fo * 16 + (lane & 15);
          hcl[base + o] = f2bf(fmaxf(acc[fm][fo][r], 0.f));
        }
      }
  } else {
    float* outp = (float*)outv + (size_t)kz * M_TOT * O;
    #pragma unroll
    for (int fm = 0; fm < 4; ++fm) {
      int ml = m0 + wm + fm * 16 + (lane & 15);
      int m = ml, b = m / PIX, pix = m - b * PIX;
      #pragma unroll
      for (int fo = 0; fo < NFO; ++fo)
        #pragma unroll
        for (int r = 0; r < 4; ++r) {
          int o = o0 + wo + fo * 16 + (lane >> 4) * 4 + r;
          outp[((size_t)b * O + o) * PIX + pix] = acc[fm][fo][r];
        }
    }
  }
}

// ---------------- sum 4 K-split partials -> NCHW fp32 out -----------------
__global__ __launch_bounds__(256) void reduce_out4(
    const float* __restrict__ part, float* __restrict__ out, int n)
{
  int i = (blockIdx.x * 256 + threadIdx.x) * 4;
  if (i < n) {
    f32x4 a = *(const f32x4*)(part + i);
    f32x4 b = *(const f32x4*)(part + n + i);
    f32x4 c = *(const f32x4*)(part + 2 * (size_t)n + i);
    f32x4 d = *(const f32x4*)(part + 3 * (size_t)n + i);
    *(f32x4*)(out + i) = (a + b) + (c + d);
  }
}

extern "C" void kernel_launch(void* const* d_in, const int* in_sizes, int n_in,
                              void* d_out, int out_size, void* d_ws, size_t ws_size,
                              hipStream_t stream)
{
  const float* x    = (const float*)d_in[0];
  const float* w_p1 = (const float*)d_in[1];
  const float* b_p1 = (const float*)d_in[2];
  const float* w_m1 = (const float*)d_in[3];
  const float* b_m1 = (const float*)d_in[4];
  const float* w_c1 = (const float*)d_in[5];
  const float* w_p2 = (const float*)d_in[6];
  const float* b_p2 = (const float*)d_in[7];
  const float* w_m2 = (const float*)d_in[8];
  const float* b_m2 = (const float*)d_in[9];
  const float* w_c2 = (const float*)d_in[10];
  float* out = (float*)d_out;

  char* ws = (char*)d_ws;
  auto align_up = [](size_t v) { return (v + 255) & ~(size_t)255; };
  size_t off = 0;
  unsigned short* xclp = (unsigned short*)(ws + off); off += align_up((size_t)B * PPIX * C1 * 2);
  unsigned short* hclp = (unsigned short*)(ws + off); off += align_up((size_t)B * PPIX * HID * 2);
  float* pmpart = (float*)(ws + off); off += align_up((size_t)4 * M_TOT * 32 * 4);
  int4*   tabO = (int4*)(ws + off);   off += align_up((size_t)M_TOT * NK * 16);
  float4* tabG = (float4*)(ws + off); off += align_up((size_t)M_TOT * NK * 16);
  unsigned short* wr1 = (unsigned short*)(ws + off); off += align_up((size_t)HID * K1 * 2);
  unsigned short* wr2 = (unsigned short*)(ws + off); off += align_up((size_t)OUT2 * K2 * 2);
  unsigned short* wpr1 = (unsigned short*)(ws + off); off += align_up((size_t)32 * K1 * 2);
  unsigned short* wpr2 = (unsigned short*)(ws + off); off += align_up((size_t)32 * K2 * 2);
  float* outpart = (float*)(ws + off); off += align_up((size_t)4 * M_TOT * OUT2 * 4);

  // zero pad rings (full-buffer zero; interiors overwritten below)
  zero_kernel<<<(int)((size_t)B * PPIX * C1 * 2 / 16 + 255) / 256, 256, 0, stream>>>(
      (u32x4*)xclp, (int)((size_t)B * PPIX * C1 * 2 / 16));
  zero_kernel<<<(int)((size_t)B * PPIX * HID * 2 / 16 + 255) / 256, 256, 0, stream>>>(
      (u32x4*)hclp, (int)((size_t)B * PPIX * HID * 2 / 16));

  // prep (weights + input transpose)
  xpose_kernel<<<dim3(25, C1 / 32, B), 256, 0, stream>>>(x, xclp, C1);
  wrep_kernel<<<HID, 256, 0, stream>>>(w_c1, wr1, C1);
  wrep_kernel<<<OUT2, 256, 0, stream>>>(w_c2, wr2, HID);
  wprep_kernel<<<32, 256, 0, stream>>>(w_p1, w_m1, wpr1, C1);
  wprep_kernel<<<32, 256, 0, stream>>>(w_p2, w_m2, wpr2, HID);

  // ---- layer 1 ----
  pconv_mfma<C1, 4><<<dim3(M_TOT / 128, 4), 256, 0, stream>>>(xclp, wpr1, pmpart);
  mktab_kernel<4><<<(M_TOT * NK + 255) / 256, 256, 0, stream>>>(pmpart, b_p1, b_m1, tabO, tabG);
  dgemm_fused<128, 0, C1><<<dim3(M_TOT / 128, HID / 128, 1), 256, 0, stream>>>(
      xclp, tabO, tabG, wr1, hclp, HID, 1);

  // ---- layer 2 ----
  pconv_mfma<HID, 4><<<dim3(M_TOT / 128, 4), 256, 0, stream>>>(hclp, wpr2, pmpart);
  mktab_kernel<4><<<(M_TOT * NK + 255) / 256, 256, 0, stream>>>(pmpart, b_p2, b_m2, tabO, tabG);
  dgemm_fused<128, 1, HID><<<dim3(M_TOT / 128, OUT2 / 128, 4), 256, 0, stream>>>(
      hclp, tabO, tabG, wr2, outpart, OUT2, 4);
  reduce_out4<<<(M_TOT * OUT2 / 4 + 255) / 256, 256, 0, stream>>>(
      outpart, out, M_TOT * OUT2);
}

// Round 5
// 224.839 us; speedup vs baseline: 1.7513x; 1.7513x over previous
//
#include <hip/hip_runtime.h>
#include <hip/hip_bf16.h>
#include <math.h>

#define B 8
#define HH 28
#define WDIM 28
#define PIX 784
#define PPIX 900          // 30*30 padded
#define M_TOT 6272
#define NK 9
#define C1 256
#define HID 1024
#define OUT2 256
#define K1 (C1*NK)   // 2304
#define K2 (HID*NK)  // 9216

typedef short short8_t __attribute__((ext_vector_type(8)));
typedef unsigned short us8 __attribute__((ext_vector_type(8)));
typedef float f32x4 __attribute__((ext_vector_type(4)));
typedef unsigned int u32x4 __attribute__((ext_vector_type(4)));

__device__ inline float bf2f(unsigned short u){ union{unsigned i; float f;} w; w.i=((unsigned)u)<<16; return w.f; }
__device__ inline unsigned short f2bf(float f){ union{float ff; unsigned i;} w; w.ff=f; unsigned u=w.i; return (unsigned short)((u + 0x7FFFu + ((u>>16)&1u))>>16); }

__device__ inline void gload16(const void* g, void* l) {
  __builtin_amdgcn_global_load_lds((const __attribute__((address_space(1))) void*)g,
                                   (__attribute__((address_space(3))) void*)l, 16, 0, 0);
}

// ---------------- zero fill (pad rings) ----------------
__global__ __launch_bounds__(256) void zero_kernel(u32x4* __restrict__ p, int n16)
{
  int i = blockIdx.x * 256 + threadIdx.x;
  if (i < n16) p[i] = u32x4{0u, 0u, 0u, 0u};
}

// ---------------- transpose x: [B][C][784] fp32 -> padded [B][900][C] bf16
__global__ __launch_bounds__(256) void xpose_kernel(
    const float* __restrict__ x, unsigned short* __restrict__ xclp, int C)
{
  __shared__ unsigned short tile[32][33];
  int b = blockIdx.z, c0 = blockIdx.y * 32, p0 = blockIdx.x * 32;
  int tx = threadIdx.x & 31, ty = threadIdx.x >> 5;
  for (int i = ty; i < 32; i += 8) {
    int c = c0 + i, p = p0 + tx;
    unsigned short v = 0;
    if (p < PIX) v = f2bf(x[((size_t)b * C + c) * PIX + p]);
    tile[i][tx] = v;
  }
  __syncthreads();
  for (int i = ty; i < 32; i += 8) {
    int p = p0 + i, c = c0 + tx;
    if (p < PIX) {
      int h = p / WDIM, w = p % WDIM;
      xclp[((size_t)b * PPIX + (h + 1) * 30 + (w + 1)) * C + c] = tile[tx][i];
    }
  }
}

// ---------------- w_c repack: [O][C][9] fp32 -> [O][n*C+c] bf16 -----------
__global__ __launch_bounds__(256) void wrep_kernel(
    const float* __restrict__ w, unsigned short* __restrict__ wr, int C)
{
  int o = blockIdx.x;
  int K = 9 * C;
  for (int k = threadIdx.x; k < K; k += 256) {
    int n = k / C, c = k % C;
    wr[(size_t)o * K + k] = f2bf(w[((size_t)o * C + c) * 9 + n]);
  }
}

// ---------------- pconv weight repack: -> [32][9*C] bf16 (rows 27..31 = 0)
__global__ __launch_bounds__(256) void wprep_kernel(
    const float* __restrict__ wp, const float* __restrict__ wm,
    unsigned short* __restrict__ wpr, int C)
{
  int ch = blockIdx.x;
  int K = 9 * C;
  const float* src = nullptr;
  if (ch < 18) src = wp + (size_t)ch * C * 9;
  else if (ch < 27) src = wm + (size_t)(ch - 18) * C * 9;
  for (int k = threadIdx.x; k < K; k += 256) {
    int n = k / C, c = k % C;
    unsigned short v = 0;
    if (src) v = f2bf(src[(size_t)c * 9 + n]);
    wpr[(size_t)ch * K + k] = v;
  }
}

// ------ pconv as skinny MFMA GEMM (2-phase dbuf): [M][9C] x [32][9C]^T ----
template<int C, int KSPLIT>
__global__ __launch_bounds__(256) void pconv_mfma(
    const unsigned short* __restrict__ xclp, // [B*900][C] padded
    const unsigned short* __restrict__ wpr,  // [32][9C]
    float* __restrict__ pmpart)              // [KSPLIT][M][32]
{
  __shared__ unsigned short As[2][128 * 64];
  __shared__ unsigned short Ws[2][32 * 64];
  const int K = 9 * C;
  int t = threadIdx.x, lane = t & 63, wv = t >> 6;
  int m0 = blockIdx.x * 128;
  int kz = blockIdx.y;
  int wm = (wv & 1) * 64, wo = (wv >> 1) * 16;
  f32x4 acc[4];
  #pragma unroll
  for (int i = 0; i < 4; ++i) acc[i] = {0.f, 0.f, 0.f, 0.f};
  long pbase[4];
  #pragma unroll
  for (int i = 0; i < 4; ++i) {
    int L = i * 256 + t, row = L >> 3;
    int m = m0 + row, b = m / PIX, pix = m - b * PIX;
    int h = pix / WDIM, w = pix - h * WDIM;
    pbase[i] = ((long)b * PPIX + (h + 1) * 30 + (w + 1)) * C;
  }
  auto stage = [&](int buf, int kk) {
    int n = kk / C, c0 = kk - n * C;
    long doff = (long)(((n / 3) - 1) * 30 + (n % 3) - 1) * C + c0;
    #pragma unroll
    for (int i = 0; i < 4; ++i) {
      int L = i * 256 + t, row = L >> 3, ch = L & 7;
      const char* src = (const char*)(xclp + pbase[i] + doff) + ((ch ^ (row & 7)) << 4);
      gload16(src, (char*)As[buf] + (size_t)(i * 256 + (wv << 6)) * 16);
    }
    {
      int row = t >> 3, ch = t & 7;
      const char* src = (const char*)(wpr + (size_t)row * K + kk) + ((ch ^ (row & 7)) << 4);
      gload16(src, (char*)Ws[buf] + (size_t)(wv << 6) * 16);
    }
  };

  int kbeg = kz * (K / KSPLIT), kend = kbeg + K / KSPLIT;
  stage(0, kbeg);
  asm volatile("s_waitcnt vmcnt(0)" ::: "memory");
  __syncthreads();
  int cur = 0;
  for (int k0 = kbeg; k0 < kend; k0 += 64, cur ^= 1) {
    if (k0 + 64 < kend) stage(cur ^ 1, k0 + 64);
    #pragma unroll
    for (int ks = 0; ks < 2; ++ks) {
      short8_t af[4], bq;
      {
        int row = wo + (lane & 15), ch = ks * 4 + (lane >> 4);
        bq = *(const short8_t*)((const char*)Ws[cur] + row * 128 + ((ch ^ (row & 7)) << 4));
      }
      #pragma unroll
      for (int fm = 0; fm < 4; ++fm) {
        int row = wm + fm * 16 + (lane & 15), ch = ks * 4 + (lane >> 4);
        af[fm] = *(const short8_t*)((const char*)As[cur] + row * 128 + ((ch ^ (row & 7)) << 4));
      }
      #pragma unroll
      for (int fm = 0; fm < 4; ++fm)
        acc[fm] = __builtin_amdgcn_mfma_f32_16x16x32_bf16(af[fm], bq, acc[fm], 0, 0, 0);
    }
    asm volatile("s_waitcnt vmcnt(0)" ::: "memory");
    __syncthreads();
  }
  float* dst = pmpart + (size_t)kz * M_TOT * 32;
  #pragma unroll
  for (int fm = 0; fm < 4; ++fm)
    #pragma unroll
    for (int r = 0; r < 4; ++r) {
      int ml = m0 + wm + fm * 16 + (lane >> 4) * 4 + r;
      int o = wo + (lane & 15);
      dst[(size_t)ml * 32 + o] = acc[fm][r];
    }
}

// ------- bilinear table: ABSOLUTE padded-pixel corner indices + gains -----
template<int KSPLIT>
__global__ __launch_bounds__(256) void mktab_kernel(
    const float* __restrict__ pmpart,
    const float* __restrict__ b_p, const float* __restrict__ b_m,
    int4* __restrict__ tabOff, float4* __restrict__ tabG)
{
  int i = blockIdx.x * 256 + threadIdx.x;
  if (i >= M_TOT * NK) return;
  int m = i / NK, n = i % NK;
  int bidx = m / PIX;
  int pix = m % PIX;
  int hh = pix / WDIM, ww = pix % WDIM;
  float ox = 0.f, oy = 0.f, om = 0.f;
  #pragma unroll
  for (int kz = 0; kz < KSPLIT; ++kz) {
    const float* q = pmpart + (size_t)kz * M_TOT * 32 + (size_t)m * 32;
    ox += q[n]; oy += q[9 + n]; om += q[18 + n];
  }
  float px = ox + b_p[n]     + (float)(hh + 1) + (float)(n / 3 - 1);
  float py = oy + b_p[9 + n] + (float)(ww + 1) + (float)(n % 3 - 1);
  float msk = 1.f / (1.f + expf(-(om + b_m[n])));
  float fx = floorf(px), fy = floorf(py);
  float qlx = fminf(fmaxf(fx, 0.f), 29.f);
  float qly = fminf(fmaxf(fy, 0.f), 29.f);
  float qrx = fminf(fmaxf(fx + 1.f, 0.f), 29.f);
  float qry = fminf(fmaxf(fy + 1.f, 0.f), 29.f);
  float pxc = fminf(fmaxf(px, 0.f), 29.f);
  float pyc = fminf(fmaxf(py, 0.f), 29.f);
  float glt = (1.f + (qlx - pxc)) * (1.f + (qly - pyc));
  float grb = (1.f - (qrx - pxc)) * (1.f - (qry - pyc));
  float glb = (1.f + (qlx - pxc)) * (1.f - (qry - pyc));
  float grt = (1.f - (qrx - pxc)) * (1.f + (qly - pyc));
  int ax = (int)qlx, ay = (int)qly, bx = (int)qrx, by = (int)qry;
  int pb = bidx * PPIX;
  tabOff[i] = make_int4(pb + ax * 30 + ay, pb + bx * 30 + by,
                        pb + ax * 30 + by, pb + bx * 30 + ay);
  tabG[i]   = make_float4(glt * msk, grb * msk, glb * msk, grt * msk);
}

// ---------------- sampler: 16B gathers -> A[m][k=n*CIN+c] bf16 ------------
template<int CIN>
__global__ __launch_bounds__(256) void sample_cl_kernel(
    const unsigned short* __restrict__ xclp, // [B*900][CIN] padded
    const int4* __restrict__ tabO, const float4* __restrict__ tabG,
    unsigned short* __restrict__ A,          // [mc][9*CIN]
    int mbase)
{
  constexpr int LPM = CIN / 8;         // lanes per m-row (32 or 128)
  constexpr int MPB = 256 / LPM;       // m-rows per block (8 or 2)
  int mi = threadIdx.x / LPM;
  int c0 = (threadIdx.x % LPM) * 8;
  int mloc = blockIdx.x * MPB + mi;
  int m = mbase + mloc;
  const int4*  to = tabO + (size_t)m * NK;
  const float4* tg = tabG + (size_t)m * NK;
  unsigned short* Arow = A + (size_t)mloc * (NK * CIN);
  #pragma unroll
  for (int n = 0; n < NK; ++n) {
    int4 o = to[n]; float4 g = tg[n];
    us8 a0 = *(const us8*)(xclp + (size_t)o.x * CIN + c0);
    us8 a1 = *(const us8*)(xclp + (size_t)o.y * CIN + c0);
    us8 a2 = *(const us8*)(xclp + (size_t)o.z * CIN + c0);
    us8 a3 = *(const us8*)(xclp + (size_t)o.w * CIN + c0);
    us8 r;
    #pragma unroll
    for (int j = 0; j < 8; ++j) {
      float v = g.x * bf2f(a0[j]) + g.y * bf2f(a1[j])
              + g.z * bf2f(a2[j]) + g.w * bf2f(a3[j]);
      r[j] = f2bf(v);
    }
    *(us8*)(Arow + n * CIN + c0) = r;
  }
}

// ---------------- MFMA GEMM (2-phase double-buffered) ---------------------
// A: [mc][K] bf16, Wr: [O][K] bf16.
// VAR=0: out = padded hclp [B*900][O] bf16 (+ReLU), ksplit must be 1
// VAR=1: out = fp32 partials [ksplit][B][O][784] NCHW
template<int TN, int VAR>
__global__ __launch_bounds__(256) void gemm_mfma(
    const unsigned short* __restrict__ A,
    const unsigned short* __restrict__ Wr,
    void* __restrict__ outv,
    int K, int O, int mbase, int ksplit)
{
  __shared__ unsigned short As[2][128 * 64];
  __shared__ unsigned short Ws[2][TN * 64];
  constexpr int NFO = TN / 32;
  int t = threadIdx.x, lane = t & 63, wv = t >> 6;
  int m0 = blockIdx.x * 128, o0 = blockIdx.y * TN;
  int kz = blockIdx.z;
  int wm = (wv & 1) * 64, wo = (wv >> 1) * (TN / 2);
  f32x4 acc[4][NFO];
  #pragma unroll
  for (int i = 0; i < 4; ++i)
    #pragma unroll
    for (int j = 0; j < NFO; ++j)
      acc[i][j] = {0.f, 0.f, 0.f, 0.f};

  auto stage = [&](int buf, int kk) {
    #pragma unroll
    for (int i = 0; i < 4; ++i) {
      int L = i * 256 + t, row = L >> 3, ch = L & 7;
      const char* src = (const char*)(A + (size_t)(m0 + row) * K + kk) + ((ch ^ (row & 7)) << 4);
      gload16(src, (char*)As[buf] + (size_t)(i * 256 + (wv << 6)) * 16);
    }
    #pragma unroll
    for (int i = 0; i < TN / 32; ++i) {
      int L = i * 256 + t, row = L >> 3, ch = L & 7;
      const char* src = (const char*)(Wr + (size_t)(o0 + row) * K + kk) + ((ch ^ (row & 7)) << 4);
      gload16(src, (char*)Ws[buf] + (size_t)(i * 256 + (wv << 6)) * 16);
    }
  };

  int kn = K / ksplit;
  int kbeg = kz * kn, kend = kbeg + kn;
  stage(0, kbeg);
  asm volatile("s_waitcnt vmcnt(0)" ::: "memory");
  __syncthreads();
  int cur = 0;
  for (int k0 = kbeg; k0 < kend; k0 += 64, cur ^= 1) {
    if (k0 + 64 < kend) stage(cur ^ 1, k0 + 64);
    #pragma unroll
    for (int ks = 0; ks < 2; ++ks) {
      short8_t af[4], bq[NFO];
      #pragma unroll
      for (int fm = 0; fm < 4; ++fm) {
        int row = wm + fm * 16 + (lane & 15), ch = ks * 4 + (lane >> 4);
        af[fm] = *(const short8_t*)((const char*)As[cur] + row * 128 + ((ch ^ (row & 7)) << 4));
      }
      #pragma unroll
      for (int fo = 0; fo < NFO; ++fo) {
        int row = wo + fo * 16 + (lane & 15), ch = ks * 4 + (lane >> 4);
        bq[fo] = *(const short8_t*)((const char*)Ws[cur] + row * 128 + ((ch ^ (row & 7)) << 4));
      }
      #pragma unroll
      for (int fm = 0; fm < 4; ++fm)
        #pragma unroll
        for (int fo = 0; fo < NFO; ++fo)
          acc[fm][fo] = (VAR == 0)
            ? __builtin_amdgcn_mfma_f32_16x16x32_bf16(af[fm], bq[fo], acc[fm][fo], 0, 0, 0)
            : __builtin_amdgcn_mfma_f32_16x16x32_bf16(bq[fo], af[fm], acc[fm][fo], 0, 0, 0);
    }
    asm volatile("s_waitcnt vmcnt(0)" ::: "memory");
    __syncthreads();
  }

  if (VAR == 0) {
    unsigned short* hcl = (unsigned short*)outv;
    #pragma unroll
    for (int fm = 0; fm < 4; ++fm)
      #pragma unroll
      for (int r = 0; r < 4; ++r) {
        int ml = m0 + wm + fm * 16 + (lane >> 4) * 4 + r;
        int m = mbase + ml, b = m / PIX, pix = m - b * PIX;
        int h = pix / WDIM, w = pix - h * WDIM;
        size_t base = ((size_t)b * PPIX + (h + 1) * 30 + (w + 1)) * (size_t)O;
        #pragma unroll
        for (int fo = 0; fo < NFO; ++fo) {
          int o = o0 + wo + fo * 16 + (lane & 15);
          hcl[base + o] = f2bf(fmaxf(acc[fm][fo][r], 0.f));
        }
      }
  } else {
    float* outp = (float*)outv + (size_t)kz * M_TOT * O;
    #pragma unroll
    for (int fm = 0; fm < 4; ++fm) {
      int ml = m0 + wm + fm * 16 + (lane & 15);
      int m = mbase + ml, b = m / PIX, pix = m - b * PIX;
      #pragma unroll
      for (int fo = 0; fo < NFO; ++fo)
        #pragma unroll
        for (int r = 0; r < 4; ++r) {
          int o = o0 + wo + fo * 16 + (lane >> 4) * 4 + r;
          outp[((size_t)b * O + o) * PIX + pix] = acc[fm][fo][r];
        }
    }
  }
}

// ---------------- sum 4 K-split partials -> NCHW fp32 out -----------------
__global__ __launch_bounds__(256) void reduce_out4(
    const float* __restrict__ part, float* __restrict__ out, int n)
{
  int i = (blockIdx.x * 256 + threadIdx.x) * 4;
  if (i < n) {
    f32x4 a = *(const f32x4*)(part + i);
    f32x4 b = *(const f32x4*)(part + n + i);
    f32x4 c = *(const f32x4*)(part + 2 * (size_t)n + i);
    f32x4 d = *(const f32x4*)(part + 3 * (size_t)n + i);
    *(f32x4*)(out + i) = (a + b) + (c + d);
  }
}

extern "C" void kernel_launch(void* const* d_in, const int* in_sizes, int n_in,
                              void* d_out, int out_size, void* d_ws, size_t ws_size,
                              hipStream_t stream)
{
  const float* x    = (const float*)d_in[0];
  const float* w_p1 = (const float*)d_in[1];
  const float* b_p1 = (const float*)d_in[2];
  const float* w_m1 = (const float*)d_in[3];
  const float* b_m1 = (const float*)d_in[4];
  const float* w_c1 = (const float*)d_in[5];
  const float* w_p2 = (const float*)d_in[6];
  const float* b_p2 = (const float*)d_in[7];
  const float* w_m2 = (const float*)d_in[8];
  const float* b_m2 = (const float*)d_in[9];
  const float* w_c2 = (const float*)d_in[10];
  float* out = (float*)d_out;

  char* ws = (char*)d_ws;
  auto align_up = [](size_t v) { return (v + 255) & ~(size_t)255; };
  size_t off = 0;
  unsigned short* xclp = (unsigned short*)(ws + off); off += align_up((size_t)B * PPIX * C1 * 2);
  unsigned short* hclp = (unsigned short*)(ws + off); off += align_up((size_t)B * PPIX * HID * 2);
  float* pmpart = (float*)(ws + off); off += align_up((size_t)8 * M_TOT * 32 * 4);
  int4*   tabO = (int4*)(ws + off);   off += align_up((size_t)M_TOT * NK * 16);
  float4* tabG = (float4*)(ws + off); off += align_up((size_t)M_TOT * NK * 16);
  unsigned short* wr1 = (unsigned short*)(ws + off); off += align_up((size_t)HID * K1 * 2);
  unsigned short* wr2 = (unsigned short*)(ws + off); off += align_up((size_t)OUT2 * K2 * 2);
  unsigned short* wpr1 = (unsigned short*)(ws + off); off += align_up((size_t)32 * K1 * 2);
  unsigned short* wpr2 = (unsigned short*)(ws + off); off += align_up((size_t)32 * K2 * 2);
  float* outpart = (float*)(ws + off); off += align_up((size_t)4 * M_TOT * OUT2 * 4);
  unsigned short* Abuf = (unsigned short*)(ws + off);
  size_t avail = (ws_size > off) ? ws_size - off : 0;
  auto pick_nc = [&](size_t K) {
    const int cands[3] = {1, 7, 49};
    for (int i = 0; i < 3; ++i)
      if ((size_t)(M_TOT / cands[i]) * K * 2 <= avail) return cands[i];
    return 49;
  };
  int nc1 = pick_nc(K1), nc2 = pick_nc(K2);

  // zero pad rings (full-buffer zero; interiors overwritten below)
  zero_kernel<<<(int)((size_t)B * PPIX * C1 * 2 / 16 + 255) / 256, 256, 0, stream>>>(
      (u32x4*)xclp, (int)((size_t)B * PPIX * C1 * 2 / 16));
  zero_kernel<<<(int)((size_t)B * PPIX * HID * 2 / 16 + 255) / 256, 256, 0, stream>>>(
      (u32x4*)hclp, (int)((size_t)B * PPIX * HID * 2 / 16));

  // prep (weights + input transpose)
  xpose_kernel<<<dim3(25, C1 / 32, B), 256, 0, stream>>>(x, xclp, C1);
  wrep_kernel<<<HID, 256, 0, stream>>>(w_c1, wr1, C1);
  wrep_kernel<<<OUT2, 256, 0, stream>>>(w_c2, wr2, HID);
  wprep_kernel<<<32, 256, 0, stream>>>(w_p1, w_m1, wpr1, C1);
  wprep_kernel<<<32, 256, 0, stream>>>(w_p2, w_m2, wpr2, HID);

  // ---- layer 1 ----
  pconv_mfma<C1, 4><<<dim3(M_TOT / 128, 4), 256, 0, stream>>>(xclp, wpr1, pmpart);
  mktab_kernel<4><<<(M_TOT * NK + 255) / 256, 256, 0, stream>>>(pmpart, b_p1, b_m1, tabO, tabG);
  {
    int mc = M_TOT / nc1;
    for (int ci = 0; ci < nc1; ++ci) {
      int mb = ci * mc;
      sample_cl_kernel<C1><<<mc / 8, 256, 0, stream>>>(xclp, tabO, tabG, Abuf, mb);
      gemm_mfma<128, 0><<<dim3(mc / 128, HID / 128, 1), 256, 0, stream>>>(
          Abuf, wr1, hclp, K1, HID, mb, 1);
    }
  }
  // ---- layer 2 ----
  pconv_mfma<HID, 8><<<dim3(M_TOT / 128, 8), 256, 0, stream>>>(hclp, wpr2, pmpart);
  mktab_kernel<8><<<(M_TOT * NK + 255) / 256, 256, 0, stream>>>(pmpart, b_p2, b_m2, tabO, tabG);
  {
    int mc = M_TOT / nc2;
    for (int ci = 0; ci < nc2; ++ci) {
      int mb = ci * mc;
      sample_cl_kernel<HID><<<mc / 2, 256, 0, stream>>>(hclp, tabO, tabG, Abuf, mb);
      gemm_mfma<128, 1><<<dim3(mc / 128, OUT2 / 128, 4), 256, 0, stream>>>(
          Abuf, wr2, outpart, K2, OUT2, mb, 4);
    }
  }
  reduce_out4<<<(M_TOT * OUT2 / 4 + 255) / 256, 256, 0, stream>>>(
      outpart, out, M_TOT * OUT2);
}

// Round 6
// 179.275 us; speedup vs baseline: 2.1965x; 1.2542x over previous
//
#include <hip/hip_runtime.h>
#include <hip/hip_bf16.h>
#include <math.h>

#define B 8
#define HH 28
#define WDIM 28
#define PIX 784
#define PPIX 900          // 30*30 padded
#define M_TOT 6272
#define MPADY 7296        // 57*128 >= B*PPIX, for the dense Y-GEMM
#define NK 9
#define C1 256
#define HID 1024
#define OUT2 256
#define K1 (C1*NK)   // 2304
#define NY 2560      // 9*256 deform cols + 243 pconv cols + 13 pad

typedef short short8_t __attribute__((ext_vector_type(8)));
typedef unsigned short us8 __attribute__((ext_vector_type(8)));
typedef unsigned short us4 __attribute__((ext_vector_type(4)));
typedef float f32x4 __attribute__((ext_vector_type(4)));
typedef unsigned int u32x4 __attribute__((ext_vector_type(4)));

__device__ inline float bf2f(unsigned short u){ union{unsigned i; float f;} w; w.i=((unsigned)u)<<16; return w.f; }
__device__ inline unsigned short f2bf(float f){ union{float ff; unsigned i;} w; w.ff=f; unsigned u=w.i; return (unsigned short)((u + 0x7FFFu + ((u>>16)&1u))>>16); }

__device__ inline void gload16(const void* g, void* l) {
  __builtin_amdgcn_global_load_lds((const __attribute__((address_space(1))) void*)g,
                                   (__attribute__((address_space(3))) void*)l, 16, 0, 0);
}

// ---------------- zero fill ----------------
__global__ __launch_bounds__(256) void zero_kernel(u32x4* __restrict__ p, int n16)
{
  int i = blockIdx.x * 256 + threadIdx.x;
  if (i < n16) p[i] = u32x4{0u, 0u, 0u, 0u};
}

// ---------------- transpose x: [B][C][784] fp32 -> padded [B][900][C] bf16
__global__ __launch_bounds__(256) void xpose_kernel(
    const float* __restrict__ x, unsigned short* __restrict__ xclp, int C)
{
  __shared__ unsigned short tile[32][33];
  int b = blockIdx.z, c0 = blockIdx.y * 32, p0 = blockIdx.x * 32;
  int tx = threadIdx.x & 31, ty = threadIdx.x >> 5;
  for (int i = ty; i < 32; i += 8) {
    int c = c0 + i, p = p0 + tx;
    unsigned short v = 0;
    if (p < PIX) v = f2bf(x[((size_t)b * C + c) * PIX + p]);
    tile[i][tx] = v;
  }
  __syncthreads();
  for (int i = ty; i < 32; i += 8) {
    int p = p0 + i, c = c0 + tx;
    if (p < PIX) {
      int h = p / WDIM, w = p % WDIM;
      xclp[((size_t)b * PPIX + (h + 1) * 30 + (w + 1)) * C + c] = tile[tx][i];
    }
  }
}

// ---------------- w_c1 repack: [O][C][9] fp32 -> [O][n*C+c] bf16 ----------
__global__ __launch_bounds__(256) void wrep_kernel(
    const float* __restrict__ w, unsigned short* __restrict__ wr, int C)
{
  int o = blockIdx.x;
  int K = 9 * C;
  for (int k = threadIdx.x; k < K; k += 256) {
    int n = k / C, c = k % C;
    wr[(size_t)o * K + k] = f2bf(w[((size_t)o * C + c) * 9 + n]);
  }
}

// ------- pconv1 weight repack: -> [32][9*C] bf16 (rows 27..31 = 0) --------
__global__ __launch_bounds__(256) void wprep_kernel(
    const float* __restrict__ wp, const float* __restrict__ wm,
    unsigned short* __restrict__ wpr, int C)
{
  int ch = blockIdx.x;
  int K = 9 * C;
  const float* src = nullptr;
  if (ch < 18) src = wp + (size_t)ch * C * 9;
  else if (ch < 27) src = wm + (size_t)(ch - 18) * C * 9;
  for (int k = threadIdx.x; k < K; k += 256) {
    int n = k / C, c = k % C;
    unsigned short v = 0;
    if (src) v = f2bf(src[(size_t)c * 9 + n]);
    wpr[(size_t)ch * K + k] = v;
  }
}

// ------- layer-2 combined W: [NY=2560][1024] bf16 -------------------------
// rows 0..2303: j = n*256+o -> w_c2[o][c][n];  rows 2304..2546: jj=j-2304,
// n=jj/27, ch=jj%27 -> w_p2/w_m2;  rows 2547..2559: zero
__global__ __launch_bounds__(256) void wy2prep_kernel(
    const float* __restrict__ wc2, const float* __restrict__ wp2,
    const float* __restrict__ wm2, unsigned short* __restrict__ wy)
{
  int j = blockIdx.x;
  const float* src = nullptr;
  if (j < 2304) {
    int n = j >> 8, o = j & 255;
    src = wc2 + (size_t)o * HID * 9 + n;
  } else if (j < 2547) {
    int jj = j - 2304, n = jj / 27, ch = jj % 27;
    src = (ch < 18) ? wp2 + (size_t)ch * HID * 9 + n
                    : wm2 + (size_t)(ch - 18) * HID * 9 + n;
  }
  for (int c = threadIdx.x; c < HID; c += 256)
    wy[(size_t)j * HID + c] = src ? f2bf(src[(size_t)c * 9]) : (unsigned short)0;
}

// ------ pconv1 as skinny MFMA GEMM (2-phase dbuf): [M][9C] x [32][9C]^T ---
template<int C, int KSPLIT>
__global__ __launch_bounds__(256) void pconv_mfma(
    const unsigned short* __restrict__ xclp,
    const unsigned short* __restrict__ wpr,
    float* __restrict__ pmpart)              // [KSPLIT][M][32]
{
  __shared__ unsigned short As[2][128 * 64];
  __shared__ unsigned short Ws[2][32 * 64];
  const int K = 9 * C;
  int t = threadIdx.x, lane = t & 63, wv = t >> 6;
  int m0 = blockIdx.x * 128;
  int kz = blockIdx.y;
  int wm = (wv & 1) * 64, wo = (wv >> 1) * 16;
  f32x4 acc[4];
  #pragma unroll
  for (int i = 0; i < 4; ++i) acc[i] = {0.f, 0.f, 0.f, 0.f};
  long pbase[4];
  #pragma unroll
  for (int i = 0; i < 4; ++i) {
    int L = i * 256 + t, row = L >> 3;
    int m = m0 + row, b = m / PIX, pix = m - b * PIX;
    int h = pix / WDIM, w = pix - h * WDIM;
    pbase[i] = ((long)b * PPIX + (h + 1) * 30 + (w + 1)) * C;
  }
  auto stage = [&](int buf, int kk) {
    int n = kk / C, c0 = kk - n * C;
    long doff = (long)(((n / 3) - 1) * 30 + (n % 3) - 1) * C + c0;
    #pragma unroll
    for (int i = 0; i < 4; ++i) {
      int L = i * 256 + t, row = L >> 3, ch = L & 7;
      const char* src = (const char*)(xclp + pbase[i] + doff) + ((ch ^ (row & 7)) << 4);
      gload16(src, (char*)As[buf] + (size_t)(i * 256 + (wv << 6)) * 16);
    }
    {
      int row = t >> 3, ch = t & 7;
      const char* src = (const char*)(wpr + (size_t)row * K + kk) + ((ch ^ (row & 7)) << 4);
      gload16(src, (char*)Ws[buf] + (size_t)(wv << 6) * 16);
    }
  };

  int kbeg = kz * (K / KSPLIT), kend = kbeg + K / KSPLIT;
  stage(0, kbeg);
  asm volatile("s_waitcnt vmcnt(0)" ::: "memory");
  __syncthreads();
  int cur = 0;
  for (int k0 = kbeg; k0 < kend; k0 += 64, cur ^= 1) {
    if (k0 + 64 < kend) stage(cur ^ 1, k0 + 64);
    #pragma unroll
    for (int ks = 0; ks < 2; ++ks) {
      short8_t af[4], bq;
      {
        int row = wo + (lane & 15), ch = ks * 4 + (lane >> 4);
        bq = *(const short8_t*)((const char*)Ws[cur] + row * 128 + ((ch ^ (row & 7)) << 4));
      }
      #pragma unroll
      for (int fm = 0; fm < 4; ++fm) {
        int row = wm + fm * 16 + (lane & 15), ch = ks * 4 + (lane >> 4);
        af[fm] = *(const short8_t*)((const char*)As[cur] + row * 128 + ((ch ^ (row & 7)) << 4));
      }
      #pragma unroll
      for (int fm = 0; fm < 4; ++fm)
        acc[fm] = __builtin_amdgcn_mfma_f32_16x16x32_bf16(af[fm], bq, acc[fm], 0, 0, 0);
    }
    asm volatile("s_waitcnt vmcnt(0)" ::: "memory");
    __syncthreads();
  }
  float* dst = pmpart + (size_t)kz * M_TOT * 32;
  #pragma unroll
  for (int fm = 0; fm < 4; ++fm)
    #pragma unroll
    for (int r = 0; r < 4; ++r) {
      int ml = m0 + wm + fm * 16 + (lane >> 4) * 4 + r;
      int o = wo + (lane & 15);
      dst[(size_t)ml * 32 + o] = acc[fm][r];
    }
}

// ------- pconv2 reduce: sum fixed-shift taps of Y's pconv cols -> pm ------
__global__ __launch_bounds__(256) void pred2_kernel(
    const unsigned short* __restrict__ Y,  // [MPADY][NY]
    float* __restrict__ pm)                // [M][32]
{
  int idx = blockIdx.x * 256 + threadIdx.x;
  if (idx >= M_TOT * 27) return;
  int m = idx / 27, ch = idx % 27;
  int b = m / PIX, pix = m % PIX;
  int h = pix / WDIM, w = pix % WDIM;
  int q0 = b * PPIX + (h + 1) * 30 + (w + 1);
  float s = 0.f;
  #pragma unroll
  for (int n = 0; n < NK; ++n) {
    int q = q0 + (n / 3 - 1) * 30 + (n % 3 - 1);
    s += bf2f(Y[(size_t)q * NY + 2304 + n * 27 + ch]);
  }
  pm[(size_t)m * 32 + ch] = s;
}

// ------- bilinear table: ABSOLUTE padded-pixel corner indices + gains -----
template<int KSPLIT>
__global__ __launch_bounds__(256) void mktab_kernel(
    const float* __restrict__ pmpart,
    const float* __restrict__ b_p, const float* __restrict__ b_m,
    int4* __restrict__ tabOff, float4* __restrict__ tabG)
{
  int i = blockIdx.x * 256 + threadIdx.x;
  if (i >= M_TOT * NK) return;
  int m = i / NK, n = i % NK;
  int bidx = m / PIX;
  int pix = m % PIX;
  int hh = pix / WDIM, ww = pix % WDIM;
  float ox = 0.f, oy = 0.f, om = 0.f;
  #pragma unroll
  for (int kz = 0; kz < KSPLIT; ++kz) {
    const float* q = pmpart + (size_t)kz * M_TOT * 32 + (size_t)m * 32;
    ox += q[n]; oy += q[9 + n]; om += q[18 + n];
  }
  float px = ox + b_p[n]     + (float)(hh + 1) + (float)(n / 3 - 1);
  float py = oy + b_p[9 + n] + (float)(ww + 1) + (float)(n % 3 - 1);
  float msk = 1.f / (1.f + expf(-(om + b_m[n])));
  float fx = floorf(px), fy = floorf(py);
  float qlx = fminf(fmaxf(fx, 0.f), 29.f);
  float qly = fminf(fmaxf(fy, 0.f), 29.f);
  float qrx = fminf(fmaxf(fx + 1.f, 0.f), 29.f);
  float qry = fminf(fmaxf(fy + 1.f, 0.f), 29.f);
  float pxc = fminf(fmaxf(px, 0.f), 29.f);
  float pyc = fminf(fmaxf(py, 0.f), 29.f);
  float glt = (1.f + (qlx - pxc)) * (1.f + (qly - pyc));
  float grb = (1.f - (qrx - pxc)) * (1.f - (qry - pyc));
  float glb = (1.f + (qlx - pxc)) * (1.f - (qry - pyc));
  float grt = (1.f - (qrx - pxc)) * (1.f + (qly - pyc));
  int ax = (int)qlx, ay = (int)qly, bx = (int)qrx, by = (int)qry;
  int pb = bidx * PPIX;
  tabOff[i] = make_int4(pb + ax * 30 + ay, pb + bx * 30 + by,
                        pb + ax * 30 + by, pb + bx * 30 + ay);
  tabG[i]   = make_float4(glt * msk, grb * msk, glb * msk, grt * msk);
}

// ---------------- sampler (layer 1): 16B gathers -> A[m][k=n*C+c] bf16 ----
template<int CIN>
__global__ __launch_bounds__(256) void sample_cl_kernel(
    const unsigned short* __restrict__ xclp,
    const int4* __restrict__ tabO, const float4* __restrict__ tabG,
    unsigned short* __restrict__ A)
{
  constexpr int LPM = CIN / 8;
  constexpr int MPB = 256 / LPM;
  int mi = threadIdx.x / LPM;
  int c0 = (threadIdx.x % LPM) * 8;
  int m = blockIdx.x * MPB + mi;
  const int4*  to = tabO + (size_t)m * NK;
  const float4* tg = tabG + (size_t)m * NK;
  unsigned short* Arow = A + (size_t)m * (NK * CIN);
  #pragma unroll
  for (int n = 0; n < NK; ++n) {
    int4 o = to[n]; float4 g = tg[n];
    us8 a0 = *(const us8*)(xclp + (size_t)o.x * CIN + c0);
    us8 a1 = *(const us8*)(xclp + (size_t)o.y * CIN + c0);
    us8 a2 = *(const us8*)(xclp + (size_t)o.z * CIN + c0);
    us8 a3 = *(const us8*)(xclp + (size_t)o.w * CIN + c0);
    us8 r;
    #pragma unroll
    for (int j = 0; j < 8; ++j) {
      float v = g.x * bf2f(a0[j]) + g.y * bf2f(a1[j])
              + g.z * bf2f(a2[j]) + g.w * bf2f(a3[j]);
      r[j] = f2bf(v);
    }
    *(us8*)(Arow + n * CIN + c0) = r;
  }
}

// ---------------- MFMA GEMM (2-phase double-buffered) ---------------------
// A: [m][K] bf16 (row stride K), Wr: [O][K] bf16.
// VAR=0: out = padded hclp [.][O] bf16 (+ReLU)     [layer-1 deform GEMM]
// VAR=2: out = flat Y [m][O] bf16, no activation   [layer-2 dense Y-GEMM]
template<int TN, int VAR>
__global__ __launch_bounds__(256) void gemm_mfma(
    const unsigned short* __restrict__ A,
    const unsigned short* __restrict__ Wr,
    void* __restrict__ outv,
    int K, int O)
{
  __shared__ unsigned short As[2][128 * 64];
  __shared__ unsigned short Ws[2][TN * 64];
  constexpr int NFO = TN / 32;
  int t = threadIdx.x, lane = t & 63, wv = t >> 6;
  int m0 = blockIdx.x * 128, o0 = blockIdx.y * TN;
  int wm = (wv & 1) * 64, wo = (wv >> 1) * (TN / 2);
  f32x4 acc[4][NFO];
  #pragma unroll
  for (int i = 0; i < 4; ++i)
    #pragma unroll
    for (int j = 0; j < NFO; ++j)
      acc[i][j] = {0.f, 0.f, 0.f, 0.f};

  auto stage = [&](int buf, int kk) {
    #pragma unroll
    for (int i = 0; i < 4; ++i) {
      int L = i * 256 + t, row = L >> 3, ch = L & 7;
      const char* src = (const char*)(A + (size_t)(m0 + row) * K + kk) + ((ch ^ (row & 7)) << 4);
      gload16(src, (char*)As[buf] + (size_t)(i * 256 + (wv << 6)) * 16);
    }
    #pragma unroll
    for (int i = 0; i < TN / 32; ++i) {
      int L = i * 256 + t, row = L >> 3, ch = L & 7;
      const char* src = (const char*)(Wr + (size_t)(o0 + row) * K + kk) + ((ch ^ (row & 7)) << 4);
      gload16(src, (char*)Ws[buf] + (size_t)(i * 256 + (wv << 6)) * 16);
    }
  };

  stage(0, 0);
  asm volatile("s_waitcnt vmcnt(0)" ::: "memory");
  __syncthreads();
  int cur = 0;
  for (int k0 = 0; k0 < K; k0 += 64, cur ^= 1) {
    if (k0 + 64 < K) stage(cur ^ 1, k0 + 64);
    #pragma unroll
    for (int ks = 0; ks < 2; ++ks) {
      short8_t af[4], bq[NFO];
      #pragma unroll
      for (int fm = 0; fm < 4; ++fm) {
        int row = wm + fm * 16 + (lane & 15), ch = ks * 4 + (lane >> 4);
        af[fm] = *(const short8_t*)((const char*)As[cur] + row * 128 + ((ch ^ (row & 7)) << 4));
      }
      #pragma unroll
      for (int fo = 0; fo < NFO; ++fo) {
        int row = wo + fo * 16 + (lane & 15), ch = ks * 4 + (lane >> 4);
        bq[fo] = *(const short8_t*)((const char*)Ws[cur] + row * 128 + ((ch ^ (row & 7)) << 4));
      }
      #pragma unroll
      for (int fm = 0; fm < 4; ++fm)
        #pragma unroll
        for (int fo = 0; fo < NFO; ++fo)
          acc[fm][fo] = __builtin_amdgcn_mfma_f32_16x16x32_bf16(af[fm], bq[fo], acc[fm][fo], 0, 0, 0);
    }
    asm volatile("s_waitcnt vmcnt(0)" ::: "memory");
    __syncthreads();
  }

  if (VAR == 0) {
    unsigned short* hcl = (unsigned short*)outv;
    #pragma unroll
    for (int fm = 0; fm < 4; ++fm)
      #pragma unroll
      for (int r = 0; r < 4; ++r) {
        int m = m0 + wm + fm * 16 + (lane >> 4) * 4 + r;
        int b = m / PIX, pix = m - b * PIX;
        int h = pix / WDIM, w = pix - h * WDIM;
        size_t base = ((size_t)b * PPIX + (h + 1) * 30 + (w + 1)) * (size_t)O;
        #pragma unroll
        for (int fo = 0; fo < NFO; ++fo) {
          int o = o0 + wo + fo * 16 + (lane & 15);
          hcl[base + o] = f2bf(fmaxf(acc[fm][fo][r], 0.f));
        }
      }
  } else {
    unsigned short* yout = (unsigned short*)outv;
    #pragma unroll
    for (int fm = 0; fm < 4; ++fm)
      #pragma unroll
      for (int r = 0; r < 4; ++r) {
        int m = m0 + wm + fm * 16 + (lane >> 4) * 4 + r;
        #pragma unroll
        for (int fo = 0; fo < NFO; ++fo) {
          int o = o0 + wo + fo * 16 + (lane & 15);
          yout[(size_t)m * O + o] = f2bf(acc[fm][fo][r]);
        }
      }
  }
}

// ------- deform epilogue: out[b][o][pix] = sum_n sum_cor g * Y[q][n*256+o]
__global__ __launch_bounds__(256) void depi2_kernel(
    const unsigned short* __restrict__ Y,  // [MPADY][NY]
    const int4* __restrict__ tabO, const float4* __restrict__ tabG,
    float* __restrict__ out)               // [B][256][784]
{
  __shared__ float tile[256][4];
  int m0 = blockIdx.x * 4;
  int b = m0 / PIX, pix0 = m0 % PIX;
  int g = threadIdx.x >> 6, lane = threadIdx.x & 63;
  int m = m0 + g;
  const int4*  to = tabO + (size_t)m * NK;
  const float4* tg = tabG + (size_t)m * NK;
  f32x4 acc = {0.f, 0.f, 0.f, 0.f};
  #pragma unroll
  for (int n = 0; n < NK; ++n) {
    int4 o4 = to[n]; float4 g4 = tg[n];
    int col = n * 256 + lane * 4;
    us4 y0 = *(const us4*)(Y + (size_t)o4.x * NY + col);
    us4 y1 = *(const us4*)(Y + (size_t)o4.y * NY + col);
    us4 y2 = *(const us4*)(Y + (size_t)o4.z * NY + col);
    us4 y3 = *(const us4*)(Y + (size_t)o4.w * NY + col);
    #pragma unroll
    for (int j = 0; j < 4; ++j)
      acc[j] += g4.x * bf2f(y0[j]) + g4.y * bf2f(y1[j])
              + g4.z * bf2f(y2[j]) + g4.w * bf2f(y3[j]);
  }
  #pragma unroll
  for (int j = 0; j < 4; ++j) tile[lane * 4 + j][g] = acc[j];
  __syncthreads();
  int o = threadIdx.x;
  float4 v = *(const float4*)&tile[o][0];
  *(float4*)&out[((size_t)b * OUT2 + o) * PIX + pix0] = v;
}

extern "C" void kernel_launch(void* const* d_in, const int* in_sizes, int n_in,
                              void* d_out, int out_size, void* d_ws, size_t ws_size,
                              hipStream_t stream)
{
  const float* x    = (const float*)d_in[0];
  const float* w_p1 = (const float*)d_in[1];
  const float* b_p1 = (const float*)d_in[2];
  const float* w_m1 = (const float*)d_in[3];
  const float* b_m1 = (const float*)d_in[4];
  const float* w_c1 = (const float*)d_in[5];
  const float* w_p2 = (const float*)d_in[6];
  const float* b_p2 = (const float*)d_in[7];
  const float* w_m2 = (const float*)d_in[8];
  const float* b_m2 = (const float*)d_in[9];
  const float* w_c2 = (const float*)d_in[10];
  float* out = (float*)d_out;

  char* ws = (char*)d_ws;
  auto align_up = [](size_t v) { return (v + 255) & ~(size_t)255; };
  size_t off = 0;
  unsigned short* xclp = (unsigned short*)(ws + off); off += align_up((size_t)B * PPIX * C1 * 2);
  unsigned short* hclp = (unsigned short*)(ws + off); off += align_up((size_t)MPADY * HID * 2);
  unsigned short* Y    = (unsigned short*)(ws + off); off += align_up((size_t)MPADY * NY * 2);
  float* pmpart = (float*)(ws + off); off += align_up((size_t)4 * M_TOT * 32 * 4);
  float* pm2    = (float*)(ws + off); off += align_up((size_t)M_TOT * 32 * 4);
  int4*   tabO = (int4*)(ws + off);   off += align_up((size_t)M_TOT * NK * 16);
  float4* tabG = (float4*)(ws + off); off += align_up((size_t)M_TOT * NK * 16);
  unsigned short* wr1  = (unsigned short*)(ws + off); off += align_up((size_t)HID * K1 * 2);
  unsigned short* wy2  = (unsigned short*)(ws + off); off += align_up((size_t)NY * HID * 2);
  unsigned short* wpr1 = (unsigned short*)(ws + off); off += align_up((size_t)32 * K1 * 2);
  unsigned short* Abuf = (unsigned short*)(ws + off); off += align_up((size_t)M_TOT * K1 * 2);

  // zero padded buffers (rings + tail rows; interiors overwritten)
  zero_kernel<<<(int)((size_t)B * PPIX * C1 * 2 / 16 + 255) / 256, 256, 0, stream>>>(
      (u32x4*)xclp, (int)((size_t)B * PPIX * C1 * 2 / 16));
  zero_kernel<<<(int)((size_t)MPADY * HID * 2 / 16 + 255) / 256, 256, 0, stream>>>(
      (u32x4*)hclp, (int)((size_t)MPADY * HID * 2 / 16));

  // prep
  xpose_kernel<<<dim3(25, C1 / 32, B), 256, 0, stream>>>(x, xclp, C1);
  wrep_kernel<<<HID, 256, 0, stream>>>(w_c1, wr1, C1);
  wprep_kernel<<<32, 256, 0, stream>>>(w_p1, w_m1, wpr1, C1);
  wy2prep_kernel<<<NY, 256, 0, stream>>>(w_c2, w_p2, w_m2, wy2);

  // ---- layer 1 (materialized-A deformable GEMM) ----
  pconv_mfma<C1, 4><<<dim3(M_TOT / 128, 4), 256, 0, stream>>>(xclp, wpr1, pmpart);
  mktab_kernel<4><<<(M_TOT * NK + 255) / 256, 256, 0, stream>>>(pmpart, b_p1, b_m1, tabO, tabG);
  sample_cl_kernel<C1><<<M_TOT / 8, 256, 0, stream>>>(xclp, tabO, tabG, Abuf);
  gemm_mfma<128, 0><<<dim3(M_TOT / 128, HID / 128), 256, 0, stream>>>(
      Abuf, wr1, hclp, K1, HID);

  // ---- layer 2 (factorized: dense per-tap Y-GEMM + gather epilogues) ----
  gemm_mfma<128, 2><<<dim3(MPADY / 128, NY / 128), 256, 0, stream>>>(
      hclp, wy2, Y, HID, NY);
  pred2_kernel<<<(M_TOT * 27 + 255) / 256, 256, 0, stream>>>(Y, pm2);
  mktab_kernel<1><<<(M_TOT * NK + 255) / 256, 256, 0, stream>>>(pm2, b_p2, b_m2, tabO, tabG);
  depi2_kernel<<<M_TOT / 4, 256, 0, stream>>>(Y, tabO, tabG, out);
}